// Round 6
// baseline (598.065 us; speedup 1.0000x reference)
//
#include <hip/hip_runtime.h>
#include <hip/hip_bf16.h>

#define N_EMBD 1024
#define N_HEADS 16
#define HD 64
#define TSEQ 2048
#define BATCH 4
#define M_TOT (BATCH*TSEQ)   // 8192

typedef short s16x8 __attribute__((ext_vector_type(8)));
typedef float f32x4 __attribute__((ext_vector_type(4)));

__device__ __forceinline__ void glds16(const void* g, void* l) {
  __builtin_amdgcn_global_load_lds((const __attribute__((address_space(1))) void*)g,
                                   (__attribute__((address_space(3))) void*)l, 16, 0, 0);
}

__device__ __forceinline__ unsigned pkbf16(float a, float b) {
  __hip_bfloat162 h; h.x = __float2bfloat16(a); h.y = __float2bfloat16(b);
  unsigned u; __builtin_memcpy(&u, &h, 4); return u;
}

// ---- cast x fp32 -> bf16, 4 elems/thread ----
__global__ __launch_bounds__(256) void xcast_kernel(const float* __restrict__ x,
                                                    __hip_bfloat16* __restrict__ xb) {
  int i = blockIdx.x * 256 + threadIdx.x;
  float4 f = ((const float4*)x)[i];
  __hip_bfloat162 p0, p1;
  p0.x = __float2bfloat16(f.x); p0.y = __float2bfloat16(f.y);
  p1.x = __float2bfloat16(f.z); p1.y = __float2bfloat16(f.w);
  ((__hip_bfloat162*)xb)[2*i]   = p0;
  ((__hip_bfloat162*)xb)[2*i+1] = p1;
}

// ---- transpose + cast weights: out[n][c] = in[c][n], bf16 ----
__global__ void wcast_kernel(const float* __restrict__ Wq, const float* __restrict__ Wk,
                             const float* __restrict__ Wv, const float* __restrict__ Wp,
                             __hip_bfloat16* __restrict__ wqkvt, __hip_bfloat16* __restrict__ wpt) {
  __shared__ float tile[32][33];
  int z = blockIdx.z;
  const float* in = (z==0)?Wq:(z==1)?Wk:(z==2)?Wv:Wp;
  __hip_bfloat16* out = (z<3) ? (wqkvt + (size_t)z*N_EMBD*N_EMBD) : wpt;
  int tx = threadIdx.x, ty = threadIdx.y;
  int x  = blockIdx.x*32 + tx;
  int y0 = blockIdx.y*32;
  #pragma unroll
  for (int j=0;j<4;++j) tile[ty + j*8][tx] = in[(size_t)(y0+ty+j*8)*N_EMBD + x];
  __syncthreads();
  int xo  = y0 + tx;
  int yo0 = blockIdx.x*32;
  #pragma unroll
  for (int j=0;j<4;++j)
    out[(size_t)(yo0+ty+j*8)*N_EMBD + xo] = __float2bfloat16(tile[tx][ty+j*8]);
}

// ---- bf16 MFMA GEMM, m97-style: 128x128 tile, BK=64, glds16 staging ----
// (unchanged from R4)
__global__ __launch_bounds__(256) void gemm_kernel(
    const __hip_bfloat16* __restrict__ A,   // [M][1024] bf16
    const __hip_bfloat16* __restrict__ Bt,  // [N][1024] bf16 (transposed weight)
    __hip_bfloat16* __restrict__ Qb, __hip_bfloat16* __restrict__ Kb,
    __hip_bfloat16* __restrict__ Vt,        // [B,H,d,T]
    float* __restrict__ out, const float* __restrict__ bias, int mode) {
  __shared__ __align__(16) char smem[32768];
  __hip_bfloat16* Alin = (__hip_bfloat16*)smem;            // 128x64
  __hip_bfloat16* Blin = (__hip_bfloat16*)(smem + 16384);  // 128x64
  int tid = threadIdx.x;
  int m0 = blockIdx.y*128, n0 = blockIdx.x*128;
  int w = tid>>6, lane = tid&63, l16 = lane&15, quad = lane>>4;
  int wr = w>>1, wc = w&1;
  int xg = l16 & 7;
  int off0 = ((quad    ) ^ xg)*8;
  int off1 = ((quad + 4) ^ xg)*8;
  f32x4 acc[4][4];
  #pragma unroll
  for (int mi=0;mi<4;++mi)
    #pragma unroll
    for (int ni=0;ni<4;++ni) acc[mi][ni] = (f32x4){0.f,0.f,0.f,0.f};

  for (int k0=0; k0<N_EMBD; k0+=64) {
    __syncthreads();
    #pragma unroll
    for (int rd=0; rd<4; ++rd) {
      int slot = rd*256 + tid;
      int row  = slot>>3;
      int gc8  = ((tid&7) ^ (row&7))*8;
      glds16(A  + (size_t)(m0+row)*N_EMBD + k0 + gc8, Alin + slot*8);
      glds16(Bt + (size_t)(n0+row)*N_EMBD + k0 + gc8, Blin + slot*8);
    }
    __syncthreads();
    #pragma unroll
    for (int c=0;c<2;++c) {
      int off = c ? off1 : off0;
      s16x8 af[4], bfr[4];
      #pragma unroll
      for (int mi=0;mi<4;++mi)
        af[mi] = *(const s16x8*)(Alin + (wr*64+mi*16+l16)*64 + off);
      #pragma unroll
      for (int ni=0;ni<4;++ni)
        bfr[ni] = *(const s16x8*)(Blin + (wc*64+ni*16+l16)*64 + off);
      #pragma unroll
      for (int mi=0;mi<4;++mi)
        #pragma unroll
        for (int ni=0;ni<4;++ni)
          acc[mi][ni] = __builtin_amdgcn_mfma_f32_16x16x32_bf16(af[mi], bfr[ni], acc[mi][ni],0,0,0);
    }
  }

  if (mode == 0) {
    int which = n0 >> 10;
    int bb = m0 >> 11, t0 = m0 & 2047;
    if (which < 2) {
      __hip_bfloat16* outp = (which==0)?Qb:Kb;
      #pragma unroll
      for (int mi=0;mi<4;++mi) {
        #pragma unroll
        for (int ni=0;ni<4;++ni) {
          int ncol = (n0 & 1023) + wc*64 + ni*16 + l16;
          int hh = ncol>>6, dd = ncol&63;
          #pragma unroll
          for (int r=0;r<4;++r) {
            int t = t0 + wr*64 + mi*16 + quad*4 + r;
            outp[((size_t)(bb*N_HEADS + hh)*TSEQ + t)*HD + dd] = __float2bfloat16(acc[mi][ni][r]);
          }
        }
      }
    } else {
      int hh0 = (n0 & 1023) >> 6;
      __hip_bfloat16 (*Ts)[136] = (__hip_bfloat16(*)[136])smem;
      #pragma unroll
      for (int p=0;p<2;++p) {
        __syncthreads();
        if (wc == p) {
          #pragma unroll
          for (int mi=0;mi<4;++mi)
            #pragma unroll
            for (int ni=0;ni<4;++ni) {
              int dd = ni*16 + l16;
              #pragma unroll
              for (int r=0;r<4;++r)
                Ts[dd][wr*64 + mi*16 + quad*4 + r] = __float2bfloat16(acc[mi][ni][r]);
            }
        }
        __syncthreads();
        int dd = tid>>2, tc = (tid&3)*32;
        __hip_bfloat16* dst = Vt + ((size_t)(bb*N_HEADS + hh0 + p)*HD + dd)*TSEQ + t0 + tc;
        #pragma unroll
        for (int c4=0;c4<4;++c4)
          *(uint4*)(dst + c4*8) = *(const uint4*)&Ts[dd][tc + c4*8];
      }
    }
  } else {
    #pragma unroll
    for (int mi=0;mi<4;++mi) {
      #pragma unroll
      for (int ni=0;ni<4;++ni) {
        int col = n0 + wc*64 + ni*16 + l16;
        float bs = bias[col];
        #pragma unroll
        for (int r=0;r<4;++r) {
          int m = m0 + wr*64 + mi*16 + quad*4 + r;
          out[(size_t)m*N_EMBD + col] = acc[mi][ni][r] + bs;
        }
      }
    }
  }
}

// ---- barrier-free MFMA flash attention, software-pipelined ----
// 1 wave / 32 queries per block. S^T = K Q^T, O^T = V^T P^T (R5 layout,
// verified). R6 change: __launch_bounds__(64,2) for a 256-VGPR budget and an
// explicit register pipeline — K frags double-buffered (prefetch t+1 during
// compute of t), V frags issued at top of iteration and consumed ~500 cyc
// later after S-MFMA + exp + P roundtrip. [R5 failed latency-bound: 60 VGPR
// forced serial load->wait->mfma chains; all counters <25%]
#define PST 72
__global__ __launch_bounds__(64, 2) void attn_kernel(
    const __hip_bfloat16* __restrict__ Qb, const __hip_bfloat16* __restrict__ Kb,
    const __hip_bfloat16* __restrict__ Vt, __hip_bfloat16* __restrict__ Yb) {
  __shared__ __align__(16) __hip_bfloat16 Ps[32][PST];   // [query][key]
  int lane = threadIdx.x;
  int bx = blockIdx.x, h = blockIdx.y, b = blockIdx.z;
  int qb = (bx & 1) ? (63 - (bx >> 1)) : (bx >> 1);  // interleave heavy/light bands
  int q0 = qb * 32;
  size_t bhT  = (size_t)(b*N_HEADS + h)*TSEQ;
  size_t bhHD = (size_t)(b*N_HEADS + h)*HD;
  int l16 = lane & 15, quad = lane >> 4;

  // Q B-frags: B[k=d][n=query] -> rows of Qb. qf[qi][chunk]
  s16x8 qf[2][2];
  #pragma unroll
  for (int qi=0; qi<2; ++qi) {
    const __hip_bfloat16* qrow = Qb + (bhT + q0 + qi*16 + l16)*HD;
    qf[qi][0] = *(const s16x8*)(qrow + quad*8);
    qf[qi][1] = *(const s16x8*)(qrow + 32 + quad*8);
  }

  f32x4 z4 = {0.f,0.f,0.f,0.f};
  f32x4 oacc[4][2];     // O^T: [d-tile][q-tile], row=d, col=query
  #pragma unroll
  for (int mt=0;mt<4;++mt) { oacc[mt][0]=z4; oacc[mt][1]=z4; }
  float lq[2] = {0.f, 0.f};

  const __hip_bfloat16* kbase = Kb + bhT*HD;
  const __hip_bfloat16* vbase = Vt + bhHD*TSEQ;

  int ntiles = qb/2 + 1;

  // K frag double-buffer; prologue loads tile 0
  s16x8 kbuf[2][4][2];
  #pragma unroll
  for (int kt=0; kt<4; ++kt) {
    const __hip_bfloat16* krow = kbase + (size_t)(kt*16 + l16)*HD;
    kbuf[0][kt][0] = *(const s16x8*)(krow + quad*8);
    kbuf[0][kt][1] = *(const s16x8*)(krow + 32 + quad*8);
  }

  for (int t=0; t<ntiles; ++t) {
    int k0 = t*64;
    bool diag = (t == ntiles-1);
    int cur = t & 1, nxt = cur ^ 1;

    // (1) issue V loads for tile t — consumed only at step (5)
    s16x8 vbuf[4][2];
    #pragma unroll
    for (int mt=0; mt<4; ++mt) {
      const __hip_bfloat16* vrow = vbase + (size_t)(mt*16 + l16)*TSEQ + k0;
      vbuf[mt][0] = *(const s16x8*)(vrow + quad*8);
      vbuf[mt][1] = *(const s16x8*)(vrow + 32 + quad*8);
    }

    // (2) prefetch K frags for tile t+1 — consumed next iteration
    if (t+1 < ntiles) {
      int k0n = k0 + 64;
      #pragma unroll
      for (int kt=0; kt<4; ++kt) {
        const __hip_bfloat16* krow = kbase + (size_t)(k0n + kt*16 + l16)*HD;
        kbuf[nxt][kt][0] = *(const s16x8*)(krow + quad*8);
        kbuf[nxt][kt][1] = *(const s16x8*)(krow + 32 + quad*8);
      }
    }

    // (3) S^T = K Q^T from kbuf[cur] (loaded one iteration ago)
    f32x4 sacc[4][2];
    #pragma unroll
    for (int kt=0; kt<4; ++kt) {
      #pragma unroll
      for (int qi=0; qi<2; ++qi) {
        f32x4 s = z4;
        s = __builtin_amdgcn_mfma_f32_16x16x32_bf16(kbuf[cur][kt][0], qf[qi][0], s,0,0,0);
        s = __builtin_amdgcn_mfma_f32_16x16x32_bf16(kbuf[cur][kt][1], qf[qi][1], s,0,0,0);
        sacc[kt][qi] = s;
      }
    }

    // (4) exp + l accumulate + P^T -> LDS
    #pragma unroll
    for (int kt=0; kt<4; ++kt) {
      #pragma unroll
      for (int qi=0; qi<2; ++qi) {
        float p0,p1,p2,p3;
        if (diag) {
          int keyb = k0 + kt*16 + quad*4;
          int qq   = q0 + qi*16 + l16;
          p0 = (qq >= keyb  ) ? __expf(sacc[kt][qi][0]*0.125f) : 0.f;
          p1 = (qq >= keyb+1) ? __expf(sacc[kt][qi][1]*0.125f) : 0.f;
          p2 = (qq >= keyb+2) ? __expf(sacc[kt][qi][2]*0.125f) : 0.f;
          p3 = (qq >= keyb+3) ? __expf(sacc[kt][qi][3]*0.125f) : 0.f;
        } else {
          p0 = __expf(sacc[kt][qi][0]*0.125f);
          p1 = __expf(sacc[kt][qi][1]*0.125f);
          p2 = __expf(sacc[kt][qi][2]*0.125f);
          p3 = __expf(sacc[kt][qi][3]*0.125f);
        }
        lq[qi] += (p0+p1)+(p2+p3);
        uint2 w; w.x = pkbf16(p0,p1); w.y = pkbf16(p2,p3);
        *(uint2*)&Ps[qi*16 + l16][kt*16 + quad*4] = w;   // same-wave lgkm ordering
      }
    }

    // (5) P^T B-frags back from LDS; O^T += V^T P^T from vbuf (issued at (1))
    s16x8 pb[2][2];
    #pragma unroll
    for (int c=0; c<2; ++c)
      #pragma unroll
      for (int qi=0; qi<2; ++qi)
        pb[c][qi] = *(const s16x8*)&Ps[qi*16 + l16][c*32 + quad*8];

    #pragma unroll
    for (int mt=0; mt<4; ++mt) {
      #pragma unroll
      for (int qi=0; qi<2; ++qi) {
        oacc[mt][qi] = __builtin_amdgcn_mfma_f32_16x16x32_bf16(vbuf[mt][0], pb[0][qi], oacc[mt][qi],0,0,0);
        oacc[mt][qi] = __builtin_amdgcn_mfma_f32_16x16x32_bf16(vbuf[mt][1], pb[1][qi], oacc[mt][qi],0,0,0);
      }
    }
  }

  // reduce l across the 4 quads (lanes sharing query l16)
  #pragma unroll
  for (int qi=0; qi<2; ++qi) {
    lq[qi] += __shfl_xor(lq[qi], 16);
    lq[qi] += __shfl_xor(lq[qi], 32);
  }

  // epilogue: lane holds O^T[d=mt*16+quad*4+r][q=qi*16+l16]
  #pragma unroll
  for (int qi=0; qi<2; ++qi) {
    float inv = 1.f / lq[qi];
    int tq = q0 + qi*16 + l16;
    __hip_bfloat16* yr = Yb + ((size_t)(b*TSEQ + tq))*N_EMBD + h*HD;
    #pragma unroll
    for (int mt=0; mt<4; ++mt) {
      f32x4 a = oacc[mt][qi];
      uint2 w; w.x = pkbf16(a[0]*inv, a[1]*inv); w.y = pkbf16(a[2]*inv, a[3]*inv);
      *(uint2*)(yr + mt*16 + quad*4) = w;
    }
  }
}

extern "C" void kernel_launch(void* const* d_in, const int* in_sizes, int n_in,
                              void* d_out, int out_size, void* d_ws, size_t ws_size,
                              hipStream_t stream) {
  const float* x  = (const float*)d_in[0];
  const float* Wq = (const float*)d_in[1];
  const float* Wk = (const float*)d_in[2];
  const float* Wv = (const float*)d_in[3];
  const float* Wp = (const float*)d_in[4];
  const float* bp = (const float*)d_in[5];

  char* w = (char*)d_ws;
  __hip_bfloat16* xb    = (__hip_bfloat16*)w;  w += (size_t)M_TOT*N_EMBD*2;   // 16 MB
  __hip_bfloat16* wqkvt = (__hip_bfloat16*)w;  w += (size_t)3*N_EMBD*N_EMBD*2;// 6 MB
  __hip_bfloat16* wpt   = (__hip_bfloat16*)w;  w += (size_t)N_EMBD*N_EMBD*2;  // 2 MB
  __hip_bfloat16* Qb    = (__hip_bfloat16*)w;  w += (size_t)M_TOT*N_EMBD*2;   // 16 MB
  __hip_bfloat16* Kb    = (__hip_bfloat16*)w;  w += (size_t)M_TOT*N_EMBD*2;   // 16 MB
  __hip_bfloat16* Vt    = (__hip_bfloat16*)w;  w += (size_t)M_TOT*N_EMBD*2;   // 16 MB [B,H,d,T]
  __hip_bfloat16* Yb    = (__hip_bfloat16*)w;                                  // 16 MB (88 MB total)

  xcast_kernel<<<dim3(M_TOT*N_EMBD/1024), dim3(256), 0, stream>>>(x, xb);
  wcast_kernel<<<dim3(32,32,4), dim3(32,8), 0, stream>>>(Wq,Wk,Wv,Wp,wqkvt,wpt);
  gemm_kernel<<<dim3(24,64), dim3(256), 0, stream>>>(xb, wqkvt, Qb,Kb,Vt, nullptr, nullptr, 0);
  attn_kernel<<<dim3(64,N_HEADS,BATCH), dim3(64), 0, stream>>>(Qb,Kb,Vt,Yb);
  gemm_kernel<<<dim3(8,64), dim3(256), 0, stream>>>(Yb, wpt, nullptr,nullptr,nullptr,
                                                    (float*)d_out, bp, 1);
}

// Round 7
// 407.742 us; speedup vs baseline: 1.4668x; 1.4668x over previous
//
#include <hip/hip_runtime.h>
#include <hip/hip_bf16.h>

#define N_EMBD 1024
#define N_HEADS 16
#define HD 64
#define TSEQ 2048
#define BATCH 4
#define M_TOT (BATCH*TSEQ)   // 8192

typedef short s16x8 __attribute__((ext_vector_type(8)));
typedef float f32x4 __attribute__((ext_vector_type(4)));

__device__ __forceinline__ void glds16(const void* g, void* l) {
  __builtin_amdgcn_global_load_lds((const __attribute__((address_space(1))) void*)g,
                                   (__attribute__((address_space(3))) void*)l, 16, 0, 0);
}

__device__ __forceinline__ unsigned pkbf16(float a, float b) {
  __hip_bfloat162 h; h.x = __float2bfloat16(a); h.y = __float2bfloat16(b);
  unsigned u; __builtin_memcpy(&u, &h, 4); return u;
}

// ---- cast x fp32 -> bf16, 4 elems/thread ----
__global__ __launch_bounds__(256) void xcast_kernel(const float* __restrict__ x,
                                                    __hip_bfloat16* __restrict__ xb) {
  int i = blockIdx.x * 256 + threadIdx.x;
  float4 f = ((const float4*)x)[i];
  __hip_bfloat162 p0, p1;
  p0.x = __float2bfloat16(f.x); p0.y = __float2bfloat16(f.y);
  p1.x = __float2bfloat16(f.z); p1.y = __float2bfloat16(f.w);
  ((__hip_bfloat162*)xb)[2*i]   = p0;
  ((__hip_bfloat162*)xb)[2*i+1] = p1;
}

// ---- transpose + cast weights: out[n][c] = in[c][n], bf16 ----
__global__ void wcast_kernel(const float* __restrict__ Wq, const float* __restrict__ Wk,
                             const float* __restrict__ Wv, const float* __restrict__ Wp,
                             __hip_bfloat16* __restrict__ wqkvt, __hip_bfloat16* __restrict__ wpt) {
  __shared__ float tile[32][33];
  int z = blockIdx.z;
  const float* in = (z==0)?Wq:(z==1)?Wk:(z==2)?Wv:Wp;
  __hip_bfloat16* out = (z<3) ? (wqkvt + (size_t)z*N_EMBD*N_EMBD) : wpt;
  int tx = threadIdx.x, ty = threadIdx.y;
  int x  = blockIdx.x*32 + tx;
  int y0 = blockIdx.y*32;
  #pragma unroll
  for (int j=0;j<4;++j) tile[ty + j*8][tx] = in[(size_t)(y0+ty+j*8)*N_EMBD + x];
  __syncthreads();
  int xo  = y0 + tx;
  int yo0 = blockIdx.x*32;
  #pragma unroll
  for (int j=0;j<4;++j)
    out[(size_t)(yo0+ty+j*8)*N_EMBD + xo] = __float2bfloat16(tile[tx][ty+j*8]);
}

// ---- bf16 MFMA GEMM, m97-style: 128x128 tile, BK=64, glds16 staging ----
// (unchanged from R4)
__global__ __launch_bounds__(256) void gemm_kernel(
    const __hip_bfloat16* __restrict__ A,   // [M][1024] bf16
    const __hip_bfloat16* __restrict__ Bt,  // [N][1024] bf16 (transposed weight)
    __hip_bfloat16* __restrict__ Qb, __hip_bfloat16* __restrict__ Kb,
    __hip_bfloat16* __restrict__ Vt,        // [B,H,d,T]
    float* __restrict__ out, const float* __restrict__ bias, int mode) {
  __shared__ __align__(16) char smem[32768];
  __hip_bfloat16* Alin = (__hip_bfloat16*)smem;            // 128x64
  __hip_bfloat16* Blin = (__hip_bfloat16*)(smem + 16384);  // 128x64
  int tid = threadIdx.x;
  int m0 = blockIdx.y*128, n0 = blockIdx.x*128;
  int w = tid>>6, lane = tid&63, l16 = lane&15, quad = lane>>4;
  int wr = w>>1, wc = w&1;
  int xg = l16 & 7;
  int off0 = ((quad    ) ^ xg)*8;
  int off1 = ((quad + 4) ^ xg)*8;
  f32x4 acc[4][4];
  #pragma unroll
  for (int mi=0;mi<4;++mi)
    #pragma unroll
    for (int ni=0;ni<4;++ni) acc[mi][ni] = (f32x4){0.f,0.f,0.f,0.f};

  for (int k0=0; k0<N_EMBD; k0+=64) {
    __syncthreads();
    #pragma unroll
    for (int rd=0; rd<4; ++rd) {
      int slot = rd*256 + tid;
      int row  = slot>>3;
      int gc8  = ((tid&7) ^ (row&7))*8;
      glds16(A  + (size_t)(m0+row)*N_EMBD + k0 + gc8, Alin + slot*8);
      glds16(Bt + (size_t)(n0+row)*N_EMBD + k0 + gc8, Blin + slot*8);
    }
    __syncthreads();
    #pragma unroll
    for (int c=0;c<2;++c) {
      int off = c ? off1 : off0;
      s16x8 af[4], bfr[4];
      #pragma unroll
      for (int mi=0;mi<4;++mi)
        af[mi] = *(const s16x8*)(Alin + (wr*64+mi*16+l16)*64 + off);
      #pragma unroll
      for (int ni=0;ni<4;++ni)
        bfr[ni] = *(const s16x8*)(Blin + (wc*64+ni*16+l16)*64 + off);
      #pragma unroll
      for (int mi=0;mi<4;++mi)
        #pragma unroll
        for (int ni=0;ni<4;++ni)
          acc[mi][ni] = __builtin_amdgcn_mfma_f32_16x16x32_bf16(af[mi], bfr[ni], acc[mi][ni],0,0,0);
    }
  }

  if (mode == 0) {
    int which = n0 >> 10;
    int bb = m0 >> 11, t0 = m0 & 2047;
    if (which < 2) {
      __hip_bfloat16* outp = (which==0)?Qb:Kb;
      #pragma unroll
      for (int mi=0;mi<4;++mi) {
        #pragma unroll
        for (int ni=0;ni<4;++ni) {
          int ncol = (n0 & 1023) + wc*64 + ni*16 + l16;
          int hh = ncol>>6, dd = ncol&63;
          #pragma unroll
          for (int r=0;r<4;++r) {
            int t = t0 + wr*64 + mi*16 + quad*4 + r;
            outp[((size_t)(bb*N_HEADS + hh)*TSEQ + t)*HD + dd] = __float2bfloat16(acc[mi][ni][r]);
          }
        }
      }
    } else {
      int hh0 = (n0 & 1023) >> 6;
      __hip_bfloat16 (*Ts)[136] = (__hip_bfloat16(*)[136])smem;
      #pragma unroll
      for (int p=0;p<2;++p) {
        __syncthreads();
        if (wc == p) {
          #pragma unroll
          for (int mi=0;mi<4;++mi)
            #pragma unroll
            for (int ni=0;ni<4;++ni) {
              int dd = ni*16 + l16;
              #pragma unroll
              for (int r=0;r<4;++r)
                Ts[dd][wr*64 + mi*16 + quad*4 + r] = __float2bfloat16(acc[mi][ni][r]);
            }
        }
        __syncthreads();
        int dd = tid>>2, tc = (tid&3)*32;
        __hip_bfloat16* dst = Vt + ((size_t)(bb*N_HEADS + hh0 + p)*HD + dd)*TSEQ + t0 + tc;
        #pragma unroll
        for (int c4=0;c4<4;++c4)
          *(uint4*)(dst + c4*8) = *(const uint4*)&Ts[dd][tc + c4*8];
      }
    }
  } else {
    #pragma unroll
    for (int mi=0;mi<4;++mi) {
      #pragma unroll
      for (int ni=0;ni<4;++ni) {
        int col = n0 + wc*64 + ni*16 + l16;
        float bs = bias[col];
        #pragma unroll
        for (int r=0;r<4;++r) {
          int m = m0 + wr*64 + mi*16 + quad*4 + r;
          out[(size_t)m*N_EMBD + col] = acc[mi][ni][r] + bs;
        }
      }
    }
  }
}

// ---- barrier-free MFMA flash attention, software-pipelined (fixed) ----
// 1 wave / 32 queries per block; S^T = K Q^T, O^T = V^T P^T (R5-verified math).
// R7: the R6 K double-buffer used RUNTIME indices (kbuf[cur]) -> the compiler
// demoted it to scratch (WRITE_SIZE 16->542 MB, VGPR stuck at 80). Fix:
// manual unroll-by-2 with a lambda taking swapped array REFERENCES, so buffer
// selection is compile-time and everything stays in VGPRs.
#define PST 72
__global__ __launch_bounds__(64, 2) void attn_kernel(
    const __hip_bfloat16* __restrict__ Qb, const __hip_bfloat16* __restrict__ Kb,
    const __hip_bfloat16* __restrict__ Vt, __hip_bfloat16* __restrict__ Yb) {
  __shared__ __align__(16) __hip_bfloat16 Ps[32][PST];   // [query][key]
  int lane = threadIdx.x;
  int bx = blockIdx.x, h = blockIdx.y, b = blockIdx.z;
  int qb = (bx & 1) ? (63 - (bx >> 1)) : (bx >> 1);  // interleave heavy/light bands
  int q0 = qb * 32;
  size_t bhT  = (size_t)(b*N_HEADS + h)*TSEQ;
  size_t bhHD = (size_t)(b*N_HEADS + h)*HD;
  int l16 = lane & 15, quad = lane >> 4;

  // Q B-frags: B[k=d][n=query] -> rows of Qb. qf[qi][chunk]
  s16x8 qf[2][2];
  #pragma unroll
  for (int qi=0; qi<2; ++qi) {
    const __hip_bfloat16* qrow = Qb + (bhT + q0 + qi*16 + l16)*HD;
    qf[qi][0] = *(const s16x8*)(qrow + quad*8);
    qf[qi][1] = *(const s16x8*)(qrow + 32 + quad*8);
  }

  f32x4 z4 = {0.f,0.f,0.f,0.f};
  f32x4 oacc[4][2];     // O^T: [d-tile][q-tile], row=d, col=query
  #pragma unroll
  for (int mt=0;mt<4;++mt) { oacc[mt][0]=z4; oacc[mt][1]=z4; }
  float lq[2] = {0.f, 0.f};

  const __hip_bfloat16* kbase = Kb + bhT*HD;
  const __hip_bfloat16* vbase = Vt + bhHD*TSEQ;

  int ntiles = qb/2 + 1;

  s16x8 kA[4][2], kB[4][2];      // K frag double-buffer, STATIC indexing only
  #pragma unroll
  for (int kt=0; kt<4; ++kt) {
    const __hip_bfloat16* krow = kbase + (size_t)(kt*16 + l16)*HD;
    kA[kt][0] = *(const s16x8*)(krow + quad*8);
    kA[kt][1] = *(const s16x8*)(krow + 32 + quad*8);
  }

  auto tile_body = [&](int t, s16x8 (&kc)[4][2], s16x8 (&kn)[4][2]) {
    int k0 = t*64;
    bool diag = (t == ntiles-1);

    // (1) prefetch K frags for tile t+1 into the other buffer
    if (t+1 < ntiles) {
      int k0n = k0 + 64;
      #pragma unroll
      for (int kt=0; kt<4; ++kt) {
        const __hip_bfloat16* krow = kbase + (size_t)(k0n + kt*16 + l16)*HD;
        kn[kt][0] = *(const s16x8*)(krow + quad*8);
        kn[kt][1] = *(const s16x8*)(krow + 32 + quad*8);
      }
    }

    // (2) issue V loads for tile t — consumed only at step (5)
    s16x8 vbuf[4][2];
    #pragma unroll
    for (int mt=0; mt<4; ++mt) {
      const __hip_bfloat16* vrow = vbase + (size_t)(mt*16 + l16)*TSEQ + k0;
      vbuf[mt][0] = *(const s16x8*)(vrow + quad*8);
      vbuf[mt][1] = *(const s16x8*)(vrow + 32 + quad*8);
    }

    // (3) S^T = K Q^T from kc (loaded one full iteration ago)
    f32x4 sacc[4][2];
    #pragma unroll
    for (int kt=0; kt<4; ++kt) {
      #pragma unroll
      for (int qi=0; qi<2; ++qi) {
        f32x4 s = z4;
        s = __builtin_amdgcn_mfma_f32_16x16x32_bf16(kc[kt][0], qf[qi][0], s,0,0,0);
        s = __builtin_amdgcn_mfma_f32_16x16x32_bf16(kc[kt][1], qf[qi][1], s,0,0,0);
        sacc[kt][qi] = s;
      }
    }

    // (4) exp + l accumulate + P^T -> LDS
    #pragma unroll
    for (int kt=0; kt<4; ++kt) {
      #pragma unroll
      for (int qi=0; qi<2; ++qi) {
        float p0,p1,p2,p3;
        if (diag) {
          int keyb = k0 + kt*16 + quad*4;
          int qq   = q0 + qi*16 + l16;
          p0 = (qq >= keyb  ) ? __expf(sacc[kt][qi][0]*0.125f) : 0.f;
          p1 = (qq >= keyb+1) ? __expf(sacc[kt][qi][1]*0.125f) : 0.f;
          p2 = (qq >= keyb+2) ? __expf(sacc[kt][qi][2]*0.125f) : 0.f;
          p3 = (qq >= keyb+3) ? __expf(sacc[kt][qi][3]*0.125f) : 0.f;
        } else {
          p0 = __expf(sacc[kt][qi][0]*0.125f);
          p1 = __expf(sacc[kt][qi][1]*0.125f);
          p2 = __expf(sacc[kt][qi][2]*0.125f);
          p3 = __expf(sacc[kt][qi][3]*0.125f);
        }
        lq[qi] += (p0+p1)+(p2+p3);
        uint2 w; w.x = pkbf16(p0,p1); w.y = pkbf16(p2,p3);
        *(uint2*)&Ps[qi*16 + l16][kt*16 + quad*4] = w;   // same-wave lgkm ordering
      }
    }

    // (5) P^T B-frags back from LDS; O^T += V^T P^T from vbuf (issued at (2))
    s16x8 pb[2][2];
    #pragma unroll
    for (int c=0; c<2; ++c)
      #pragma unroll
      for (int qi=0; qi<2; ++qi)
        pb[c][qi] = *(const s16x8*)&Ps[qi*16 + l16][c*32 + quad*8];

    #pragma unroll
    for (int mt=0; mt<4; ++mt) {
      #pragma unroll
      for (int qi=0; qi<2; ++qi) {
        oacc[mt][qi] = __builtin_amdgcn_mfma_f32_16x16x32_bf16(vbuf[mt][0], pb[0][qi], oacc[mt][qi],0,0,0);
        oacc[mt][qi] = __builtin_amdgcn_mfma_f32_16x16x32_bf16(vbuf[mt][1], pb[1][qi], oacc[mt][qi],0,0,0);
      }
    }
  };

  for (int t=0; t<ntiles; t+=2) {
    tile_body(t, kA, kB);                       // compute kA, prefetch kB
    if (t+1 < ntiles) tile_body(t+1, kB, kA);   // compute kB, prefetch kA
  }

  // reduce l across the 4 quads (lanes sharing query l16)
  #pragma unroll
  for (int qi=0; qi<2; ++qi) {
    lq[qi] += __shfl_xor(lq[qi], 16);
    lq[qi] += __shfl_xor(lq[qi], 32);
  }

  // epilogue: lane holds O^T[d=mt*16+quad*4+r][q=qi*16+l16]
  #pragma unroll
  for (int qi=0; qi<2; ++qi) {
    float inv = 1.f / lq[qi];
    int tq = q0 + qi*16 + l16;
    __hip_bfloat16* yr = Yb + ((size_t)(b*TSEQ + tq))*N_EMBD + h*HD;
    #pragma unroll
    for (int mt=0; mt<4; ++mt) {
      f32x4 a = oacc[mt][qi];
      uint2 w; w.x = pkbf16(a[0]*inv, a[1]*inv); w.y = pkbf16(a[2]*inv, a[3]*inv);
      *(uint2*)(yr + mt*16 + quad*4) = w;
    }
  }
}

extern "C" void kernel_launch(void* const* d_in, const int* in_sizes, int n_in,
                              void* d_out, int out_size, void* d_ws, size_t ws_size,
                              hipStream_t stream) {
  const float* x  = (const float*)d_in[0];
  const float* Wq = (const float*)d_in[1];
  const float* Wk = (const float*)d_in[2];
  const float* Wv = (const float*)d_in[3];
  const float* Wp = (const float*)d_in[4];
  const float* bp = (const float*)d_in[5];

  char* w = (char*)d_ws;
  __hip_bfloat16* xb    = (__hip_bfloat16*)w;  w += (size_t)M_TOT*N_EMBD*2;   // 16 MB
  __hip_bfloat16* wqkvt = (__hip_bfloat16*)w;  w += (size_t)3*N_EMBD*N_EMBD*2;// 6 MB
  __hip_bfloat16* wpt   = (__hip_bfloat16*)w;  w += (size_t)N_EMBD*N_EMBD*2;  // 2 MB
  __hip_bfloat16* Qb    = (__hip_bfloat16*)w;  w += (size_t)M_TOT*N_EMBD*2;   // 16 MB
  __hip_bfloat16* Kb    = (__hip_bfloat16*)w;  w += (size_t)M_TOT*N_EMBD*2;   // 16 MB
  __hip_bfloat16* Vt    = (__hip_bfloat16*)w;  w += (size_t)M_TOT*N_EMBD*2;   // 16 MB [B,H,d,T]
  __hip_bfloat16* Yb    = (__hip_bfloat16*)w;                                  // 16 MB (88 MB total)

  xcast_kernel<<<dim3(M_TOT*N_EMBD/1024), dim3(256), 0, stream>>>(x, xb);
  wcast_kernel<<<dim3(32,32,4), dim3(32,8), 0, stream>>>(Wq,Wk,Wv,Wp,wqkvt,wpt);
  gemm_kernel<<<dim3(24,64), dim3(256), 0, stream>>>(xb, wqkvt, Qb,Kb,Vt, nullptr, nullptr, 0);
  attn_kernel<<<dim3(64,N_HEADS,BATCH), dim3(64), 0, stream>>>(Qb,Kb,Vt,Yb);
  gemm_kernel<<<dim3(8,64), dim3(256), 0, stream>>>(Yb, wpt, nullptr,nullptr,nullptr,
                                                    (float*)d_out, bp, 1);
}